// Round 3
// baseline (229.672 us; speedup 1.0000x reference)
//
#include <hip/hip_runtime.h>
#include <type_traits>

// SOC scan:  SOC[b,t] = SOC_init(b) + sum_{k<=t} g[k],  g[0]=0,
//   g[t]  = (ts[t]-ts[t-1]) * f[t-1]
//   f[t]  = (c1 + c2*softplus(I*w1e0 + Te*w1e1 + b1e)) * I[t]
//   c1 = coef*(1+b2e), c2 = coef*w2e, coef = eta0/(3600*Q)
//
// R10: R9 (8-way template switch for rotation) died with a container-level
// failure — most plausible kernel-side cause is 8x code bloat (8 full
// instantiations of the unrolled scan behind a switch). Same theory, 1/8 the
// code: rotation R is now a RUNTIME arg. vals[] is stored in PROCESSING
// order (ci, compile-time) so no runtime-indexed register arrays (rule #20);
// ch=(ci+R)&7 only feeds global addresses; the logical-order fixup
// (+run2_total for run-1 chunks) happens at store time.
//
// Theory under test (from R8's neutral result): six structures pin at
// 58-70us vs 26.6us floor, insensitive to intra-block structure =>
// address-level effect. Row stride is exactly 2^17 B; 1024 co-resident
// lockstep blocks read b*2^17 + common delta -> HBM channel camping.
// Destagger: each block visits its 8 chunks in rotated order (2 runs,
// scan is separable), R=(b>>3)&7 varies within an XCD.

static __device__ __forceinline__ float bf2f(unsigned int u) {
    union { unsigned int i; float f; } v;
    v.i = u << 16;
    return v.f;
}
static __device__ __forceinline__ unsigned short f2bf(float f) {
    union { unsigned int i; float f; } v;
    v.f = f;
    unsigned int x = v.i;
    return (unsigned short)((x + 0x7fffu + ((x >> 16) & 1u)) >> 16);  // RNE
}
static __device__ __forceinline__ float sp_fast(float x) {
    return __logf(1.f + __expf(x));   // v_exp_f32 / v_log_f32, |x| << 88
}

struct F4 { float ts, I, Te, U; };
static __device__ __forceinline__ F4 dec(ushort4 x) {
    return {bf2f(x.x), bf2f(x.y), bf2f(x.z), bf2f(x.w)};
}
static __device__ __forceinline__ F4 dec(float4 x) {
    return {x.x, x.y, x.z, x.w};
}

template <bool BF16>
static __device__ __forceinline__ float ld(const void* p, int i) {
    return BF16 ? bf2f(((const unsigned short*)p)[i]) : ((const float*)p)[i];
}

constexpr int BLOCK = 256;

// ---------------- main path: f32, K=4 thread-serial, rotated chunk order --
// chunk = 256 timesteps (64 lanes x 4 consecutive); NCH chunks per wave.
// Processing order ci=0..NCH-1 maps to logical chunk ch=(ci+R)&(NCH-1):
// run1 = ci in [0, NCH-R)  (logical chunks R..NCH-1),
// run2 = ci in [NCH-R,NCH) (logical chunks 0..R-1).
template <int NCH>
static __device__ void scan_rot(
    const float* __restrict__ X, const float* __restrict__ SC,
    const float* __restrict__ W1i, const float* __restrict__ b1i,
    const float* __restrict__ W2i, const float* __restrict__ b2i,
    const float* __restrict__ W1e, const float* __restrict__ b1e,
    const float* __restrict__ W2e, const float* __restrict__ b2e,
    float* __restrict__ outv, int R, float* s_wtot, float* s_init)
{
    constexpr int SPAN = NCH * 256;       // timesteps per wave
    constexpr int T    = SPAN * 4;

    const int b    = blockIdx.x;
    const int tid  = threadIdx.x;
    const int lane = tid & 63;
    const int wave = tid >> 6;
    const int ws   = wave * SPAN;

    const float Q    = SC[b * 4 + 0];
    const float eta0 = SC[b * 4 + 1];
    const float Rsc  = SC[b * 4 + 2];
    const float S3   = SC[b * 4 + 3];
    const float w1e0 = W1e[0];
    const float w1e1 = W1e[1];
    const float vb1e = b1e[0];
    const float coef = eta0 / (3600.f * Q);
    const float c2   = coef * W2e[0];
    const float c1   = coef * (1.f + b2e[0]);

    const float4* Xrow = (const float4*)X + (size_t)b * T;

    // ring: first 2 chunks of the rotated sequence in flight before any use
    float4 ring[8];
    #pragma unroll
    for (int c = 0; c < 2; ++c) {
        const int ch = (c + R) & (NCH - 1);
        #pragma unroll
        for (int j = 0; j < 4; ++j)
            ring[c * 4 + j] = Xrow[ws + ch * 256 + lane * 4 + j];
    }

    // predecessor loads: run1 entry (element ws + R*256 - 1, only if R>0)
    // and run2 entry (element ws - 1; row start special for wave 0).
    float4 p1v = {0.f, 0.f, 0.f, 0.f};
    if (R > 0) p1v = Xrow[ws + R * 256 - 1];
    const float4 p2v = (wave > 0) ? Xrow[ws - 1] : Xrow[0];

    // run entry carries
    float ts2, f2;                        // entry state for logical chunk 0
    if (wave > 0) {
        const float hp = sp_fast(fmaf(p2v.y, w1e0, fmaf(p2v.z, w1e1, vb1e)));
        f2  = fmaf(c2, hp, c1) * p2v.y;
        ts2 = p2v.x;
    } else {
        ts2 = p2v.x;                      // makes g[0] = (ts0-ts0)*0 = 0
        f2  = 0.f;
    }
    float ts_c, f_c;                      // carry for the run being processed
    if (R > 0) {
        const float hp = sp_fast(fmaf(p1v.y, w1e0, fmaf(p1v.z, w1e1, vb1e)));
        f_c  = fmaf(c2, hp, c1) * p1v.y;
        ts_c = p1v.x;
    } else {
        ts_c = ts2;
        f_c  = f2;
    }

    float vals[NCH * 4];                  // PROCESSING order (static index)
    float carry = 0.f;
    float run1_total = 0.f;
    #pragma unroll
    for (int ci = 0; ci < NCH; ++ci) {
        if (R > 0 && ci == NCH - R) {     // run boundary: start run2
            run1_total = carry;
            carry = 0.f;
            ts_c = ts2;
            f_c  = f2;
        }
        const int s = (ci & 1) * 4;
        const float4 v0 = ring[s + 0];
        const float4 v1 = ring[s + 1];
        const float4 v2 = ring[s + 2];
        const float4 v3 = ring[s + 3];
        if (ci + 2 < NCH) {               // refill: keeps ~8 loads outstanding
            const int chn = (ci + 2 + R) & (NCH - 1);
            #pragma unroll
            for (int j = 0; j < 4; ++j)
                ring[s + j] = Xrow[ws + chn * 256 + lane * 4 + j];
        }

        const float f0  = fmaf(c2, sp_fast(fmaf(v0.y, w1e0, fmaf(v0.z, w1e1, vb1e))), c1) * v0.y;
        const float f1  = fmaf(c2, sp_fast(fmaf(v1.y, w1e0, fmaf(v1.z, w1e1, vb1e))), c1) * v1.y;
        const float fv2 = fmaf(c2, sp_fast(fmaf(v2.y, w1e0, fmaf(v2.z, w1e1, vb1e))), c1) * v2.y;
        const float f3  = fmaf(c2, sp_fast(fmaf(v3.y, w1e0, fmaf(v3.z, w1e1, vb1e))), c1) * v3.y;

        // predecessor of this thread's first element = lane-1's last element
        float pts = __shfl_up(v3.x, 1, 64);
        float pf  = __shfl_up(f3,   1, 64);
        if (lane == 0) { pts = ts_c; pf = f_c; }

        // thread-local inclusive prefix over 4 consecutive timesteps
        const float g0 = (v0.x - pts) * pf;
        const float g1 = fmaf(v1.x - v0.x, f0,  g0);
        const float g2 = fmaf(v2.x - v1.x, f1,  g1);
        const float g3 = fmaf(v3.x - v2.x, fv2, g2);

        // wave inclusive scan over thread totals
        float S = g3;
        #pragma unroll
        for (int d = 1; d < 64; d <<= 1) {
            const float u = __shfl_up(S, d, 64);
            if (lane >= d) S += u;
        }
        const float tb = carry + (S - g3);   // exclusive prefix for thread
        vals[ci * 4 + 0] = g0 + tb;
        vals[ci * 4 + 1] = g1 + tb;
        vals[ci * 4 + 2] = g2 + tb;
        vals[ci * 4 + 3] = g3 + tb;

        carry += __shfl(S, 63, 64);          // run-local carry
        ts_c   = __shfl(v3.x, 63, 64);
        f_c    = __shfl(f3, 63, 64);
    }
    // run totals: run2 covers logical chunks [0,R), run1 covers [R,NCH)
    float run2_total, wave_total;
    if (R > 0) { run2_total = carry; wave_total = run1_total + run2_total; }
    else       { run2_total = 0.f;   wave_total = carry; }

    // SOC_init (wave 0 only; p2v == Xrow[0] there)
    if (wave == 0 && lane == 0) {
        const float pre = fmaf(p2v.y, W1i[0],
                          fmaf(p2v.z, W1i[1],
                          fmaf(p2v.w, W1i[2],
                          fmaf(Rsc, W1i[3], b1i[0]))));
        const float h0 = sp_fast(pre);
        *s_init = S3 * (1.f + fmaf(h0, W2i[0], b2i[0]));
    }
    if (lane == 0) s_wtot[wave] = wave_total;
    __syncthreads();                         // the ONLY barrier

    float base = *s_init;
    #pragma unroll
    for (int w = 0; w < 3; ++w)
        if (w < wave) base += s_wtot[w];

    // destaggered, fully-coalesced float4 stores (same rotated order).
    // run1 chunks (ci < NCH-R) logically FOLLOW run2 -> add run2_total.
    float4* orow = (float4*)(outv + (size_t)b * T);
    #pragma unroll
    for (int ci = 0; ci < NCH; ++ci) {
        const int ch = (ci + R) & (NCH - 1);
        const float badd = base + ((ci < NCH - R) ? run2_total : 0.f);
        float4 o;
        o.x = vals[ci * 4 + 0] + badd;
        o.y = vals[ci * 4 + 1] + badd;
        o.z = vals[ci * 4 + 2] + badd;
        o.w = vals[ci * 4 + 3] + badd;
        orow[wave * (SPAN / 4) + ch * 64 + lane] = o;
    }
}

__global__ __launch_bounds__(BLOCK, 4) void socnet_reg(
    const void* __restrict__ X, const void* __restrict__ SC,
    const void* __restrict__ W1i, const void* __restrict__ b1i,
    const void* __restrict__ W2i, const void* __restrict__ b2i,
    const void* __restrict__ W1e, const void* __restrict__ b1e,
    const void* __restrict__ W2e, const void* __restrict__ b2e,
    void* __restrict__ out)
{
    __shared__ float s_wtot[4];
    __shared__ float s_init;
    // rotation varies WITHIN an XCD (b&7 is the XCD id -> use b>>3)
    const int r = (blockIdx.x >> 3) & 7;
    scan_rot<8>((const float*)X, (const float*)SC,
                (const float*)W1i, (const float*)b1i,
                (const float*)W2i, (const float*)b2i,
                (const float*)W1e, (const float*)b1e,
                (const float*)W2e, (const float*)b2e,
                (float*)out, r, s_wtot, &s_init);
}

// ---------------- fallback (bf16 input or odd T): serial-carry, correct ----
template <bool BF16>
static __device__ void scan_serial(
    const void* __restrict__ Xv, const void* __restrict__ SCv,
    const void* __restrict__ W1i, const void* __restrict__ b1i,
    const void* __restrict__ W2i, const void* __restrict__ b2i,
    const void* __restrict__ W1e, const void* __restrict__ b1e,
    const void* __restrict__ W2e, const void* __restrict__ b2e,
    void* __restrict__ outv, int T,
    float* s_wts, float* s_wf, float* s_wsum, float* s_carr)
{
    using XVec = typename std::conditional<BF16, ushort4, float4>::type;
    const int b = blockIdx.x, tid = threadIdx.x;
    const int lane = tid & 63, wave = tid >> 6;
    const int ntile = (T + BLOCK - 1) / BLOCK;

    const float Q    = ld<BF16>(SCv, b * 4 + 0);
    const float eta0 = ld<BF16>(SCv, b * 4 + 1);
    const float R    = ld<BF16>(SCv, b * 4 + 2);
    const float S3   = ld<BF16>(SCv, b * 4 + 3);
    const float w1e0 = ld<BF16>(W1e, 0);
    const float w1e1 = ld<BF16>(W1e, 1);
    const float vb1e = ld<BF16>(b1e, 0);
    const float coef = eta0 / (3600.f * Q);
    const float c2   = coef * ld<BF16>(W2e, 0);
    const float c1   = coef * (1.f + ld<BF16>(b2e, 0));

    const XVec* Xrow = (const XVec*)Xv + (size_t)b * T;

    for (int tile = 0; tile < ntile; ++tile) {
        const int t = tile * BLOCK + tid;
        const bool act = t < T;
        F4 v = {0.f, 0.f, 0.f, 0.f};
        if (act) v = dec(Xrow[t]);
        const float f = fmaf(c2, sp_fast(fmaf(v.I, w1e0, fmaf(v.Te, w1e1, vb1e))), c1) * v.I;

        float pts = __shfl_up(v.ts, 1, 64);
        float pf  = __shfl_up(f, 1, 64);

        __syncthreads();
        if (lane == 63) { s_wts[wave] = v.ts; s_wf[wave] = f; }
        if (tile == 0 && tid == 0) {
            const float pre = fmaf(v.I, ld<BF16>(W1i, 0),
                              fmaf(v.Te, ld<BF16>(W1i, 1),
                              fmaf(v.U, ld<BF16>(W1i, 2),
                              fmaf(R, ld<BF16>(W1i, 3), ld<BF16>(b1i, 0)))));
            s_carr[0] = S3 * (1.f + fmaf(sp_fast(pre), ld<BF16>(W2i, 0), ld<BF16>(b2i, 0)));
        }
        __syncthreads();
        if (lane == 0) {
            if (wave == 0) { if (tile > 0) { pts = s_carr[1]; pf = s_carr[2]; } }
            else { pts = s_wts[wave - 1]; pf = s_wf[wave - 1]; }
        }
        float g = (t == 0 || !act) ? 0.f : (v.ts - pts) * pf;
        #pragma unroll
        for (int d = 1; d < 64; d <<= 1) {
            const float u = __shfl_up(g, d, 64);
            if (lane >= d) g += u;
        }
        if (lane == 63) s_wsum[wave] = g;
        __syncthreads();
        float soc = s_carr[0];
        #pragma unroll
        for (int w = 0; w < 3; ++w) if (w < wave) soc += s_wsum[w];
        soc += g;
        if (act) {
            if (BF16) ((unsigned short*)outv)[(size_t)b * T + t] = f2bf(soc);
            else      ((float*)outv)[(size_t)b * T + t] = soc;
        }
        __syncthreads();
        if (tid == BLOCK - 1) { s_carr[0] = soc; s_carr[1] = v.ts; s_carr[2] = f; }
    }
}

__global__ __launch_bounds__(BLOCK) void socnet_serial_k(
    const void* __restrict__ X, const void* __restrict__ SC,
    const void* __restrict__ W1i, const void* __restrict__ b1i,
    const void* __restrict__ W2i, const void* __restrict__ b2i,
    const void* __restrict__ W1e, const void* __restrict__ b1e,
    const void* __restrict__ W2e, const void* __restrict__ b2e,
    void* __restrict__ out, int T)
{
    __shared__ float s_wts[4], s_wf[4], s_wsum[4], s_carr[3];
    const unsigned int* scw = (const unsigned int*)SC;
    const float l0 = bf2f(scw[0] & 0xFFFFu), l1 = bf2f(scw[1] & 0xFFFFu);
    const float l2 = bf2f(scw[2] & 0xFFFFu), l3 = bf2f(scw[3] & 0xFFFFu);
    const bool isbf =
        (l0 >= 0.45f && l0 <= 1.55f) && (l1 >= 0.45f && l1 <= 1.55f) &&
        (l2 >= 0.45f && l2 <= 1.55f) && (l3 >= 0.45f && l3 <= 1.55f);
    if (isbf) scan_serial<true >(X, SC, W1i, b1i, W2i, b2i, W1e, b1e, W2e, b2e,
                                 out, T, s_wts, s_wf, s_wsum, s_carr);
    else      scan_serial<false>(X, SC, W1i, b1i, W2i, b2i, W1e, b1e, W2e, b2e,
                                 out, T, s_wts, s_wf, s_wsum, s_carr);
}

extern "C" void kernel_launch(void* const* d_in, const int* in_sizes, int n_in,
                              void* d_out, int out_size, void* d_ws, size_t ws_size,
                              hipStream_t stream) {
    const int B = in_sizes[1] / 4;        // 1024
    const int T = in_sizes[0] / (B * 4);  // 8192

    if (T == 8192) {
        socnet_reg<<<dim3(B), dim3(BLOCK), 0, stream>>>(
            d_in[0], d_in[1], d_in[2], d_in[3], d_in[4], d_in[5],
            d_in[6], d_in[7], d_in[8], d_in[9], d_out);
    } else {
        socnet_serial_k<<<dim3(B), dim3(BLOCK), 0, stream>>>(
            d_in[0], d_in[1], d_in[2], d_in[3], d_in[4], d_in[5],
            d_in[6], d_in[7], d_in[8], d_in[9], d_out, T);
    }
}